// Round 5
// baseline (386.028 us; speedup 1.0000x reference)
//
#include <hip/hip_runtime.h>

// SpatialAttention (QKNorm, no 1/sqrt(d)): B=1,T=8,S=1024,HID=1152,H=16,D=72
// Pipeline: cvt x->bf16 | W^T bf16 | fused GEMM->q,k,v^T (gld16 + XOR-swizzle, 2-phase dbuf,
//           1 barrier/K-step) | fused rmsnorm q,k | flash attn (LDS dbuf, swapped QK^T) | GEMM -> f32 out

typedef __attribute__((ext_vector_type(4))) short s16x4;
typedef __attribute__((ext_vector_type(8))) short s16x8;
typedef __attribute__((ext_vector_type(4))) float f32x4;

__device__ __forceinline__ unsigned short f2b(float x) {
  unsigned u = __float_as_uint(x);
  u += 0x7FFFu + ((u >> 16) & 1u);
  return (unsigned short)(u >> 16);
}
__device__ __forceinline__ float b2f(unsigned short u) {
  return __uint_as_float(((unsigned)u) << 16);
}
__device__ __forceinline__ void gld16(const void* g, void* l) {
  __builtin_amdgcn_global_load_lds(
      (const __attribute__((address_space(1))) void*)g,
      (__attribute__((address_space(3))) void*)l, 16, 0, 0);
}

// ---------------- x -> bf16 ----------------
__global__ __launch_bounds__(256) void cvt_bf16_kernel(const float* __restrict__ in,
                                                       unsigned short* __restrict__ out,
                                                       int n8) {
  int i = blockIdx.x * 256 + threadIdx.x;
  if (i >= n8) return;
  const float4* p = (const float4*)(in + (size_t)i * 8);
  float4 a = p[0], b = p[1];
  s16x8 r;
  r[0] = (short)f2b(a.x); r[1] = (short)f2b(a.y); r[2] = (short)f2b(a.z); r[3] = (short)f2b(a.w);
  r[4] = (short)f2b(b.x); r[5] = (short)f2b(b.y); r[6] = (short)f2b(b.z); r[7] = (short)f2b(b.w);
  *(s16x8*)(out + (size_t)i * 8) = r;
}

// ---------------- W [K][N] f32 -> WT [N][K] bf16 ----------------
__global__ __launch_bounds__(256) void transpose_cvt_kernel(const float* __restrict__ W,
                                                            unsigned short* __restrict__ WT,
                                                            int K, int N) {
  __shared__ float tile[32][33];
  int n0 = blockIdx.x * 32, k0 = blockIdx.y * 32;
  int tx = threadIdx.x, ty = threadIdx.y;
#pragma unroll
  for (int i = 0; i < 4; i++)
    tile[ty + i * 8][tx] = W[(size_t)(k0 + ty + i * 8) * N + n0 + tx];
  __syncthreads();
#pragma unroll
  for (int i = 0; i < 4; i++)
    WT[(size_t)(n0 + ty + i * 8) * K + k0 + tx] = f2b(tile[tx][ty + i * 8]);
}

// ---------------- GEMM: C[M,N] = A[M,K] @ BT[N,K]^T ----------------
// gld16 staging (linear LDS dest) + XOR chunk-swizzle baked into the per-lane GLOBAL
// source address; ds_read applies the same XOR -> conflict-free fragment reads.
// 2-phase dbuf: ONE barrier per K-step; loads for kt+1 in flight across compute of kt
// (drained by compiler's vmcnt(0) at the next barrier).
// MODE 0: outF f32 row-major (no bias), N=1152.
// MODE 3: fused qkv, N=3456: col<1152 -> qn [th][s][96]; <2304 -> kn [th][s][96];
//         else -> vt [th][80][1024]. bias = [bq ; bkv].
template <int MODE>
__global__ __launch_bounds__(256) void gemm_bt_kernel(const unsigned short* __restrict__ A,
                                                      const unsigned short* __restrict__ BT,
                                                      const float* __restrict__ biasq,
                                                      const float* __restrict__ biaskv,
                                                      int N, int gx,
                                                      float* __restrict__ outF,
                                                      unsigned short* __restrict__ qn,
                                                      unsigned short* __restrict__ kn,
                                                      unsigned short* __restrict__ vt) {
  constexpr int K = 1152;
  constexpr int NT = K / 32;  // 36
  __shared__ __align__(16) unsigned short As[2][4096];  // [128 rows][32 k] linear, 16 KB each
  __shared__ __align__(16) unsigned short Bs[2][4096];
  int tid = threadIdx.x;
  int lane = tid & 63, wave = tid >> 6;
  int wr = (wave >> 1) * 64, wc = (wave & 1) * 64;
  int l15 = lane & 15, lq = lane >> 4;
  // bijective XCD swizzle (grid % 8 == 0)
  int nwg = gridDim.x;
  int bid = blockIdx.x;
  int wgid = (bid & 7) * (nwg >> 3) + (bid >> 3);
  int bx = wgid % gx, by = wgid / gx;
  int brow = by * 128, bcol = bx * 128;
  // staging: LDS slot s (16B chunks, linear) holds global chunk (s&3)^(row&3), row=s>>2.
  int r0 = tid >> 2;
  int c0 = (((tid & 3) ^ (r0 & 3)) << 3);  // u16 offset of swizzled source chunk
  const unsigned short* Ag0 = A + (size_t)(brow + r0) * K + c0;
  const unsigned short* Ag1 = A + (size_t)(brow + r0 + 64) * K + c0;
  const unsigned short* Bg0 = BT + (size_t)(bcol + r0) * K + c0;
  const unsigned short* Bg1 = BT + (size_t)(bcol + r0 + 64) * K + c0;
  int ldsL = wave * 512;          // u16 offset, half 0 (rows 0..63)
  int ldsH = 2048 + wave * 512;   // half 1 (rows 64..127)
  // fragment read offsets (within a row): lo chunk lq>>1, hi chunk 2|(lq>>1), XOR row&3(=l15&3)
  int xa = l15 & 3;
  int loff = (((lq >> 1) ^ xa) << 3) + ((lq & 1) << 2);
  int hoff = ((((lq >> 1) | 2) ^ xa) << 3) + ((lq & 1) << 2);
  // prologue: stage tile 0 into buf 0
  gld16(Ag0, &As[0][ldsL]);
  gld16(Ag1, &As[0][ldsH]);
  gld16(Bg0, &Bs[0][ldsL]);
  gld16(Bg1, &Bs[0][ldsH]);
  f32x4 acc[4][4] = {};
  for (int kt = 0; kt < NT; kt++) {
    asm volatile("s_waitcnt vmcnt(0)" ::: "memory");
    __syncthreads();
    int cur = kt & 1;
    if (kt < NT - 1) {
      int off = (kt + 1) * 32;
      int nxt = cur ^ 1;
      gld16(Ag0 + off, &As[nxt][ldsL]);
      gld16(Ag1 + off, &As[nxt][ldsH]);
      gld16(Bg0 + off, &Bs[nxt][ldsL]);
      gld16(Bg1 + off, &Bs[nxt][ldsH]);
    }
    s16x8 af[4], bf[4];
#pragma unroll
    for (int m = 0; m < 4; m++) {
      int ra = (wr + m * 16 + l15) * 32;
      s16x4 lo = *(const s16x4*)&As[cur][ra + loff];
      s16x4 hi = *(const s16x4*)&As[cur][ra + hoff];
      af[m] = __builtin_shufflevector(lo, hi, 0, 1, 2, 3, 4, 5, 6, 7);
      int rb = (wc + m * 16 + l15) * 32;
      s16x4 blo = *(const s16x4*)&Bs[cur][rb + loff];
      s16x4 bhi = *(const s16x4*)&Bs[cur][rb + hoff];
      bf[m] = __builtin_shufflevector(blo, bhi, 0, 1, 2, 3, 4, 5, 6, 7);
    }
    __builtin_amdgcn_s_setprio(1);
#pragma unroll
    for (int m = 0; m < 4; m++)
#pragma unroll
      for (int n = 0; n < 4; n++)
        acc[m][n] = __builtin_amdgcn_mfma_f32_16x16x32_bf16(af[m], bf[n], acc[m][n], 0, 0, 0);
    __builtin_amdgcn_s_setprio(0);
  }
#pragma unroll
  for (int m = 0; m < 4; m++) {
#pragma unroll
    for (int n = 0; n < 4; n++) {
#pragma unroll
      for (int r = 0; r < 4; r++) {
        int grow = brow + wr + m * 16 + (lq << 2) + r;
        int gcol = bcol + wc + n * 16 + l15;
        float v = acc[m][n][r];
        if (MODE == 0) {
          outF[(size_t)grow * N + gcol] = v;
        } else {
          v += (gcol < 1152) ? biasq[gcol] : biaskv[gcol - 1152];
          int t = grow >> 10, s = grow & 1023;
          if (gcol < 2304) {
            int c = (gcol < 1152) ? gcol : gcol - 1152;
            int h = c / 72, d = c - h * 72;
            unsigned short* dst = (gcol < 1152) ? qn : kn;
            dst[((size_t)((t * 16 + h) * 1024 + s)) * 96 + d] = f2b(v);
          } else {
            int c = gcol - 2304;
            int h = c / 72, d = c - h * 72;
            vt[((size_t)((t * 16 + h) * 80 + d)) * 1024 + s] = f2b(v);
          }
        }
      }
    }
  }
}

// ---------------- fused per-(row,head) RMSNorm for q and k, zero-fills pads ----------------
__global__ __launch_bounds__(256) void rmsnorm2_kernel(unsigned short* __restrict__ qn,
                                                       unsigned short* __restrict__ kn,
                                                       const float* __restrict__ qg,
                                                       const float* __restrict__ kg) {
  int r = blockIdx.x * 4 + (threadIdx.x >> 6);  // 0..262143
  int isK = r >= 131072;
  int g = isK ? r - 131072 : r;                 // g = th*1024 + s
  unsigned short* buf = isK ? kn : qn;
  const float* gamma = isK ? kg : qg;
  int h = (g >> 10) & 15;
  size_t base = (size_t)g * 96;
  int l = threadIdx.x & 63;
  float e0 = b2f(buf[base + l]);
  float e1 = 0.f;
  if (l < 8) e1 = b2f(buf[base + 64 + l]);
  float ss = e0 * e0 + e1 * e1;
#pragma unroll
  for (int m = 1; m < 64; m <<= 1) ss += __shfl_xor(ss, m);
  float sc = rsqrtf(ss * (1.0f / 72.0f) + 1e-6f);
  buf[base + l] = f2b(e0 * sc * gamma[h * 72 + l]);
  if (l < 32) {
    float v = 0.f;
    if (l < 8) v = e1 * sc * gamma[h * 72 + 64 + l];
    buf[base + 64 + l] = f2b(v);
  }
}

// ---------------- flash attention: LDS dbuf 2-phase, swapped QK^T, P in registers ----------------
// Qn,Kn: [th][1024][96] bf16 (pads zeroed). VtG: [th][80][1024] bf16 (rows 72..79 garbage,
// pollutes only unstored d>=72 outputs). att: [8192][1152] bf16.
__global__ __launch_bounds__(256) void attn_kernel(const unsigned short* __restrict__ Qn,
                                                   const unsigned short* __restrict__ Kn,
                                                   const unsigned short* __restrict__ VtG,
                                                   unsigned short* __restrict__ att) {
  __shared__ unsigned short Kl[2][64][100];  // pad 100: conflict-light fragment reads
  __shared__ unsigned short Vt[2][80][76];   // pad 76
  int tid = threadIdx.x;
  int lane = tid & 63, wave = tid >> 6;
  int l15 = lane & 15, lq = lane >> 4, kf = lq * 4;
  // bijective XCD swizzle: nwg=2048
  int bid = blockIdx.x;
  int orig = (bid & 7) * 256 + (bid >> 3);
  int qb = orig & 15, th = orig >> 4;
  int t = th >> 4, h = th & 15;
  const unsigned short* Q = Qn + (size_t)th * 1024 * 96;
  const unsigned short* Kp = Kn + (size_t)th * 1024 * 96;
  const unsigned short* Vg = VtG + (size_t)th * 80 * 1024;
  int qrow0 = qb * 64 + wave * 16;
  // staging chunk geometry (per thread: 3 K chunks + up to 3 V chunks)
  int krow[3], kco[3], vd[3], vco[3];
#pragma unroll
  for (int i = 0; i < 3; i++) {
    int c = tid + i * 256;           // 0..767: K chunks (64 rows x 12 chunks)
    krow[i] = c / 12;
    kco[i] = c - 12 * krow[i];
    int cc = tid + i * 256;          // 0..639: V chunks (80 rows x 8 chunks)
    vd[i] = cc >> 3;
    vco[i] = cc & 7;
  }
  bool v2 = tid < 128;               // third V chunk valid only for cc<640
  s16x8 sk[3], sv[3];
  // Q fragments (B-operand: col=l15=q, k=d)
  s16x8 qf[3];
#pragma unroll
  for (int c = 0; c < 3; c++) {
    const unsigned short* p = Q + (size_t)(qrow0 + l15) * 96 + c * 32 + kf;
    s16x4 lo = *(const s16x4*)p;
    s16x4 hi = *(const s16x4*)(p + 16);
    qf[c] = __builtin_shufflevector(lo, hi, 0, 1, 2, 3, 4, 5, 6, 7);
  }
  f32x4 o[5] = {};                   // O[q=4lq+r][d=l15+16v]
  float m_r = -3.0e38f, l_r = 0.f;   // per-lane state for q = l15

  // prologue: stage tile 0 into buf 0
#pragma unroll
  for (int i = 0; i < 3; i++)
    sk[i] = *(const s16x8*)(Kp + (size_t)krow[i] * 96 + kco[i] * 8);
#pragma unroll
  for (int i = 0; i < 2; i++)
    sv[i] = *(const s16x8*)(Vg + (size_t)vd[i] * 1024 + vco[i] * 8);
  if (v2) sv[2] = *(const s16x8*)(Vg + (size_t)vd[2] * 1024 + vco[2] * 8);
#pragma unroll
  for (int i = 0; i < 3; i++) *(s16x8*)&Kl[0][krow[i]][kco[i] * 8] = sk[i];
#pragma unroll
  for (int i = 0; i < 2; i++) *(s16x8*)&Vt[0][vd[i]][vco[i] * 8] = sv[i];
  if (v2) *(s16x8*)&Vt[0][vd[2]][vco[2] * 8] = sv[2];

  for (int tt = 0; tt < 16; tt++) {
    __syncthreads();
    int cur = tt & 1;
    if (tt < 15) {
      int kv1 = (tt + 1) * 64;
#pragma unroll
      for (int i = 0; i < 3; i++)
        sk[i] = *(const s16x8*)(Kp + (size_t)(kv1 + krow[i]) * 96 + kco[i] * 8);
#pragma unroll
      for (int i = 0; i < 2; i++)
        sv[i] = *(const s16x8*)(Vg + (size_t)vd[i] * 1024 + kv1 + vco[i] * 8);
      if (v2) sv[2] = *(const s16x8*)(Vg + (size_t)vd[2] * 1024 + kv1 + vco[2] * 8);
    }
    // S^T = mfma(K, Q): st[n][r] = S[q=l15][kv = n*16 + 4*lq + r]
    f32x4 st[4];
    __builtin_amdgcn_s_setprio(1);
#pragma unroll
    for (int n = 0; n < 4; n++) {
      f32x4 a = {};
#pragma unroll
      for (int c = 0; c < 3; c++) {
        s16x4 lo = *(const s16x4*)&Kl[cur][n * 16 + l15][c * 32 + kf];
        s16x4 hi = *(const s16x4*)&Kl[cur][n * 16 + l15][c * 32 + kf + 16];
        s16x8 kfr = __builtin_shufflevector(lo, hi, 0, 1, 2, 3, 4, 5, 6, 7);
        a = __builtin_amdgcn_mfma_f32_16x16x32_bf16(kfr, qf[c], a, 0, 0, 0);
      }
      st[n] = a;
    }
    __builtin_amdgcn_s_setprio(0);
    // online softmax for q = l15 (16 local + lq-group shfl reduce)
    float tmax = st[0][0];
#pragma unroll
    for (int n = 0; n < 4; n++)
#pragma unroll
      for (int r = 0; r < 4; r++) tmax = fmaxf(tmax, st[n][r]);
    tmax = fmaxf(tmax, __shfl_xor(tmax, 16));
    tmax = fmaxf(tmax, __shfl_xor(tmax, 32));
    float mn = fmaxf(m_r, tmax);
    float scale = __expf(m_r - mn);
    m_r = mn;
    float sum = 0.f;
#pragma unroll
    for (int n = 0; n < 4; n++)
#pragma unroll
      for (int r = 0; r < 4; r++) {
        float p = __expf(st[n][r] - mn);
        st[n][r] = p;
        sum += p;
      }
    sum += __shfl_xor(sum, 16);
    sum += __shfl_xor(sum, 32);
    l_r = l_r * scale + sum;
    // rescale O (scale for q=4lq+r lives at lane 4lq+r)
#pragma unroll
    for (int r = 0; r < 4; r++) {
      float scq = __shfl(scale, 4 * lq + r);
#pragma unroll
      for (int v = 0; v < 5; v++) o[v][r] *= scq;
    }
    // P fragments directly from st registers (A-operand: row=l15=q, k=kv)
    __builtin_amdgcn_s_setprio(1);
#pragma unroll
    for (int b = 0; b < 2; b++) {
      s16x8 pf;
#pragma unroll
      for (int j = 0; j < 8; j++) pf[j] = (short)f2b(st[2 * b + (j >> 2)][j & 3]);
#pragma unroll
      for (int v = 0; v < 5; v++) {
        s16x4 vlo = *(const s16x4*)&Vt[cur][v * 16 + l15][b * 32 + kf];
        s16x4 vhi = *(const s16x4*)&Vt[cur][v * 16 + l15][b * 32 + kf + 16];
        s16x8 vf = __builtin_shufflevector(vlo, vhi, 0, 1, 2, 3, 4, 5, 6, 7);
        o[v] = __builtin_amdgcn_mfma_f32_16x16x32_bf16(pf, vf, o[v], 0, 0, 0);
      }
    }
    __builtin_amdgcn_s_setprio(0);
    // write-late: next tile into the other buffer
    if (tt < 15) {
      int nxt = cur ^ 1;
#pragma unroll
      for (int i = 0; i < 3; i++) *(s16x8*)&Kl[nxt][krow[i]][kco[i] * 8] = sk[i];
#pragma unroll
      for (int i = 0; i < 2; i++) *(s16x8*)&Vt[nxt][vd[i]][vco[i] * 8] = sv[i];
      if (v2) *(s16x8*)&Vt[nxt][vd[2]][vco[2] * 8] = sv[2];
    }
  }
  // epilogue: normalize by l (lives at lane 4lq+r), store d<72
#pragma unroll
  for (int r = 0; r < 4; r++) {
    float inv = 1.0f / __shfl(l_r, 4 * lq + r);
    int qrow = qrow0 + 4 * lq + r;
    size_t rowbase = (size_t)(t * 1024 + qrow) * 1152 + h * 72;
#pragma unroll
    for (int v = 0; v < 5; v++) {
      int d = v * 16 + l15;
      if (d < 72) att[rowbase + d] = f2b(o[v][r] * inv);
    }
  }
}

extern "C" void kernel_launch(void* const* d_in, const int* in_sizes, int n_in,
                              void* d_out, int out_size, void* d_ws, size_t ws_size,
                              hipStream_t stream) {
  const float* x   = (const float*)d_in[0];
  const float* Wq  = (const float*)d_in[1];
  const float* bq  = (const float*)d_in[2];
  const float* Wkv = (const float*)d_in[3];
  const float* bkv = (const float*)d_in[4];
  const float* qg  = (const float*)d_in[5];
  const float* kg  = (const float*)d_in[6];
  const float* Wo  = (const float*)d_in[7];
  float* out = (float*)d_out;

  char* w = (char*)d_ws;
  unsigned short* xb   = (unsigned short*)w; w += (size_t)8192 * 1152 * 2;     // 18.9 MB
  unsigned short* WqT  = (unsigned short*)w; w += (size_t)1152 * 1152 * 2;     // contiguous with WkvT -> [3456][1152]
  unsigned short* WkvT = (unsigned short*)w; w += (size_t)2304 * 1152 * 2;
  unsigned short* WoT  = (unsigned short*)w; w += (size_t)1152 * 1152 * 2;
  unsigned short* qn   = (unsigned short*)w; w += (size_t)128 * 1024 * 96 * 2; // 25.2 MB
  unsigned short* kn   = (unsigned short*)w; w += (size_t)128 * 1024 * 96 * 2; // 25.2 MB
  unsigned short* vt   = (unsigned short*)w; w += (size_t)128 * 80 * 1024 * 2; // 21.0 MB
  unsigned short* att  = (unsigned short*)w; w += (size_t)8192 * 1152 * 2;     // 18.9 MB

  cvt_bf16_kernel<<<4608, 256, 0, stream>>>(x, xb, 9437184 / 8);
  transpose_cvt_kernel<<<dim3(36, 36), dim3(32, 8), 0, stream>>>(Wq, WqT, 1152, 1152);
  transpose_cvt_kernel<<<dim3(72, 36), dim3(32, 8), 0, stream>>>(Wkv, WkvT, 1152, 2304);
  transpose_cvt_kernel<<<dim3(36, 36), dim3(32, 8), 0, stream>>>(Wo, WoT, 1152, 1152);

  // fused q,k,v^T GEMM: BT = [WqT ; WkvT] = [3456][1152], grid 27*64=1728 (%8==0)
  gemm_bt_kernel<3><<<1728, 256, 0, stream>>>(xb, WqT, bq, bkv, 3456, 27, nullptr, qn, kn, vt);
  rmsnorm2_kernel<<<65536, 256, 0, stream>>>(qn, kn, qg, kg);

  attn_kernel<<<2048, 256, 0, stream>>>(qn, kn, vt, att);

  // out = att @ WoT^T, grid 9*64=576 (%8==0)
  gemm_bt_kernel<0><<<576, 256, 0, stream>>>(att, WoT, nullptr, nullptr, 1152, 9, out, nullptr, nullptr, nullptr);
}

// Round 6
// 334.442 us; speedup vs baseline: 1.1542x; 1.1542x over previous
//
#include <hip/hip_runtime.h>

// SpatialAttention (QKNorm, no 1/sqrt(d)): B=1,T=8,S=1024,HID=1152,H=16,D=72
// Pipeline: cvt x->bf16 | W^T bf16 | fused GEMM->q,k,v^T (reg-staged dist-2 prefetch,
//           padded LDS dbuf, supertile XCD map) | fused rmsnorm q,k |
//           flash attn (LDS dbuf, swapped QK^T, P in regs) | GEMM -> f32 out

typedef __attribute__((ext_vector_type(4))) short s16x4;
typedef __attribute__((ext_vector_type(8))) short s16x8;
typedef __attribute__((ext_vector_type(4))) float f32x4;

__device__ __forceinline__ unsigned short f2b(float x) {
  unsigned u = __float_as_uint(x);
  u += 0x7FFFu + ((u >> 16) & 1u);
  return (unsigned short)(u >> 16);
}
__device__ __forceinline__ float b2f(unsigned short u) {
  return __uint_as_float(((unsigned)u) << 16);
}

// ---------------- x -> bf16 ----------------
__global__ __launch_bounds__(256) void cvt_bf16_kernel(const float* __restrict__ in,
                                                       unsigned short* __restrict__ out,
                                                       int n8) {
  int i = blockIdx.x * 256 + threadIdx.x;
  if (i >= n8) return;
  const float4* p = (const float4*)(in + (size_t)i * 8);
  float4 a = p[0], b = p[1];
  s16x8 r;
  r[0] = (short)f2b(a.x); r[1] = (short)f2b(a.y); r[2] = (short)f2b(a.z); r[3] = (short)f2b(a.w);
  r[4] = (short)f2b(b.x); r[5] = (short)f2b(b.y); r[6] = (short)f2b(b.z); r[7] = (short)f2b(b.w);
  *(s16x8*)(out + (size_t)i * 8) = r;
}

// ---------------- W [K][N] f32 -> WT [N][K] bf16 ----------------
__global__ __launch_bounds__(256) void transpose_cvt_kernel(const float* __restrict__ W,
                                                            unsigned short* __restrict__ WT,
                                                            int K, int N) {
  __shared__ float tile[32][33];
  int n0 = blockIdx.x * 32, k0 = blockIdx.y * 32;
  int tx = threadIdx.x, ty = threadIdx.y;
#pragma unroll
  for (int i = 0; i < 4; i++)
    tile[ty + i * 8][tx] = W[(size_t)(k0 + ty + i * 8) * N + n0 + tx];
  __syncthreads();
#pragma unroll
  for (int i = 0; i < 4; i++)
    WT[(size_t)(n0 + ty + i * 8) * K + k0 + tx] = f2b(tile[tx][ty + i * 8]);
}

// ---------------- GEMM: C[M,N] = A[M,K] @ BT[N,K]^T ----------------
// Reg-staged, padded LDS [128][40] dbuf (conflict-free fragment reads), ONE barrier/K-step,
// prefetch distance 2 (loads for kt+2 in flight across step kt+1's compute).
// Supertile XCD map: per XCD, 3bx x 8by supertiles, by = xcd*8+iby -> each A-tile lives on
// one XCD's L2; active B-set ~1.2 MB. Requires grid = gx*64, gx % 3 == 0.
// MODE 0: outF f32 row-major (no bias), N=1152.
// MODE 3: fused qkv, N=3456: col<1152 -> qn [th][s][96]; <2304 -> kn [th][s][96];
//         else -> vt [th][80][1024]. bias = [bq ; bkv].
template <int MODE>
__global__ __launch_bounds__(256) void gemm_bt_kernel(const unsigned short* __restrict__ A,
                                                      const unsigned short* __restrict__ BT,
                                                      const float* __restrict__ biasq,
                                                      const float* __restrict__ biaskv,
                                                      int N, int gx,
                                                      float* __restrict__ outF,
                                                      unsigned short* __restrict__ qn,
                                                      unsigned short* __restrict__ kn,
                                                      unsigned short* __restrict__ vt) {
  constexpr int K = 1152;
  constexpr int NT = K / 32;  // 36 (even)
  __shared__ unsigned short As[2][128][40];
  __shared__ unsigned short Bs[2][128][40];
  int tid = threadIdx.x;
  int lane = tid & 63, wave = tid >> 6;
  int wr = (wave >> 1) * 64, wc = (wave & 1) * 64;
  int l15 = lane & 15, lq = lane >> 4, kf = lq * 4;
  // supertile XCD mapping (bijective: grid = gx*64, gx%3==0)
  int bid = blockIdx.x;
  int xcd = bid & 7;
  int w = bid >> 3;                 // 0 .. gx*8-1
  int st = w / 24, inner = w - st * 24;
  int ibx = inner % 3, iby = inner / 3;
  int bx = st * 3 + ibx;
  int by = xcd * 8 + iby;
  int brow = by * 128, bcol = bx * 128;
  int row0 = tid >> 2, col0 = (tid & 3) * 8;
  int row1 = row0 + 64;
  const unsigned short* Ag0 = A + (size_t)(brow + row0) * K + col0;
  const unsigned short* Ag1 = A + (size_t)(brow + row1) * K + col0;
  const unsigned short* Bg0 = BT + (size_t)(bcol + row0) * K + col0;
  const unsigned short* Bg1 = BT + (size_t)(bcol + row1) * K + col0;
  s16x8 pa0, pa1, pb0, pb1;  // set P: tiles 0,2,4,...
  s16x8 qa0, qa1, qb0, qb1;  // set Q: tiles 1,3,5,...
  // prologue: tile 0 -> LDS[0]; tile 1 -> regs Q (held)
  pa0 = *(const s16x8*)Ag0;
  pa1 = *(const s16x8*)Ag1;
  pb0 = *(const s16x8*)Bg0;
  pb1 = *(const s16x8*)Bg1;
  *(s16x8*)&As[0][row0][col0] = pa0;
  *(s16x8*)&As[0][row1][col0] = pa1;
  *(s16x8*)&Bs[0][row0][col0] = pb0;
  *(s16x8*)&Bs[0][row1][col0] = pb1;
  qa0 = *(const s16x8*)(Ag0 + 32);
  qa1 = *(const s16x8*)(Ag1 + 32);
  qb0 = *(const s16x8*)(Bg0 + 32);
  qb1 = *(const s16x8*)(Bg1 + 32);
  f32x4 acc[4][4] = {};
#define GEMM_COMPUTE(CUR)                                                        \
  {                                                                              \
    s16x8 af[4], bf[4];                                                          \
    _Pragma("unroll") for (int m = 0; m < 4; m++) {                              \
      s16x4 lo = *(const s16x4*)&As[CUR][wr + m * 16 + l15][kf];                 \
      s16x4 hi = *(const s16x4*)&As[CUR][wr + m * 16 + l15][kf + 16];            \
      af[m] = __builtin_shufflevector(lo, hi, 0, 1, 2, 3, 4, 5, 6, 7);           \
      s16x4 blo = *(const s16x4*)&Bs[CUR][wc + m * 16 + l15][kf];                \
      s16x4 bhi = *(const s16x4*)&Bs[CUR][wc + m * 16 + l15][kf + 16];           \
      bf[m] = __builtin_shufflevector(blo, bhi, 0, 1, 2, 3, 4, 5, 6, 7);         \
    }                                                                            \
    __builtin_amdgcn_s_setprio(1);                                               \
    _Pragma("unroll") for (int m = 0; m < 4; m++)                                \
        _Pragma("unroll") for (int n = 0; n < 4; n++)                            \
            acc[m][n] =                                                          \
        __builtin_amdgcn_mfma_f32_16x16x32_bf16(af[m], bf[n], acc[m][n], 0, 0, 0); \
    __builtin_amdgcn_s_setprio(0);                                               \
  }
  for (int kt = 0; kt < NT; kt += 2) {
    // even step: compute LDS[0] (tile kt); load tile kt+2 -> P; write Q (tile kt+1) -> LDS[1]
    __syncthreads();
    if (kt + 2 < NT) {
      int off = (kt + 2) * 32;
      pa0 = *(const s16x8*)(Ag0 + off);
      pa1 = *(const s16x8*)(Ag1 + off);
      pb0 = *(const s16x8*)(Bg0 + off);
      pb1 = *(const s16x8*)(Bg1 + off);
    }
    GEMM_COMPUTE(0);
    *(s16x8*)&As[1][row0][col0] = qa0;
    *(s16x8*)&As[1][row1][col0] = qa1;
    *(s16x8*)&Bs[1][row0][col0] = qb0;
    *(s16x8*)&Bs[1][row1][col0] = qb1;
    // odd step: compute LDS[1] (tile kt+1); load tile kt+3 -> Q; write P (tile kt+2) -> LDS[0]
    __syncthreads();
    if (kt + 3 < NT) {
      int off = (kt + 3) * 32;
      qa0 = *(const s16x8*)(Ag0 + off);
      qa1 = *(const s16x8*)(Ag1 + off);
      qb0 = *(const s16x8*)(Bg0 + off);
      qb1 = *(const s16x8*)(Bg1 + off);
    }
    GEMM_COMPUTE(1);
    if (kt + 2 < NT) {
      *(s16x8*)&As[0][row0][col0] = pa0;
      *(s16x8*)&As[0][row1][col0] = pa1;
      *(s16x8*)&Bs[0][row0][col0] = pb0;
      *(s16x8*)&Bs[0][row1][col0] = pb1;
    }
  }
#undef GEMM_COMPUTE
#pragma unroll
  for (int m = 0; m < 4; m++) {
#pragma unroll
    for (int n = 0; n < 4; n++) {
#pragma unroll
      for (int r = 0; r < 4; r++) {
        int grow = brow + wr + m * 16 + lq * 4 + r;
        int gcol = bcol + wc + n * 16 + l15;
        float v = acc[m][n][r];
        if (MODE == 0) {
          outF[(size_t)grow * N + gcol] = v;
        } else {
          v += (gcol < 1152) ? biasq[gcol] : biaskv[gcol - 1152];
          int t = grow >> 10, s = grow & 1023;
          if (gcol < 2304) {
            int c = (gcol < 1152) ? gcol : gcol - 1152;
            int h = c / 72, d = c - h * 72;
            unsigned short* dst = (gcol < 1152) ? qn : kn;
            dst[((size_t)((t * 16 + h) * 1024 + s)) * 96 + d] = f2b(v);
          } else {
            int c = gcol - 2304;
            int h = c / 72, d = c - h * 72;
            vt[((size_t)((t * 16 + h) * 80 + d)) * 1024 + s] = f2b(v);
          }
        }
      }
    }
  }
}

// ---------------- fused per-(row,head) RMSNorm for q and k, zero-fills pads ----------------
__global__ __launch_bounds__(256) void rmsnorm2_kernel(unsigned short* __restrict__ qn,
                                                       unsigned short* __restrict__ kn,
                                                       const float* __restrict__ qg,
                                                       const float* __restrict__ kg) {
  int r = blockIdx.x * 4 + (threadIdx.x >> 6);  // 0..262143
  int isK = r >= 131072;
  int g = isK ? r - 131072 : r;                 // g = th*1024 + s
  unsigned short* buf = isK ? kn : qn;
  const float* gamma = isK ? kg : qg;
  int h = (g >> 10) & 15;
  size_t base = (size_t)g * 96;
  int l = threadIdx.x & 63;
  float e0 = b2f(buf[base + l]);
  float e1 = 0.f;
  if (l < 8) e1 = b2f(buf[base + 64 + l]);
  float ss = e0 * e0 + e1 * e1;
#pragma unroll
  for (int m = 1; m < 64; m <<= 1) ss += __shfl_xor(ss, m);
  float sc = rsqrtf(ss * (1.0f / 72.0f) + 1e-6f);
  buf[base + l] = f2b(e0 * sc * gamma[h * 72 + l]);
  if (l < 32) {
    float v = 0.f;
    if (l < 8) v = e1 * sc * gamma[h * 72 + 64 + l];
    buf[base + 64 + l] = f2b(v);
  }
}

// ---------------- flash attention: LDS dbuf 2-phase, swapped QK^T, P in registers ----------------
// Qn,Kn: [th][1024][96] bf16 (pads zeroed). VtG: [th][80][1024] bf16 (rows 72..79 garbage,
// pollutes only unstored d>=72 outputs). att: [8192][1152] bf16.
__global__ __launch_bounds__(256) void attn_kernel(const unsigned short* __restrict__ Qn,
                                                   const unsigned short* __restrict__ Kn,
                                                   const unsigned short* __restrict__ VtG,
                                                   unsigned short* __restrict__ att) {
  __shared__ unsigned short Kl[2][64][100];  // pad 100: conflict-light fragment reads
  __shared__ unsigned short Vt[2][80][76];   // pad 76
  int tid = threadIdx.x;
  int lane = tid & 63, wave = tid >> 6;
  int l15 = lane & 15, lq = lane >> 4, kf = lq * 4;
  // bijective XCD swizzle: nwg=2048
  int bid = blockIdx.x;
  int orig = (bid & 7) * 256 + (bid >> 3);
  int qb = orig & 15, th = orig >> 4;
  int t = th >> 4, h = th & 15;
  const unsigned short* Q = Qn + (size_t)th * 1024 * 96;
  const unsigned short* Kp = Kn + (size_t)th * 1024 * 96;
  const unsigned short* Vg = VtG + (size_t)th * 80 * 1024;
  int qrow0 = qb * 64 + wave * 16;
  // staging chunk geometry (per thread: 3 K chunks + up to 3 V chunks)
  int krow[3], kco[3], vd[3], vco[3];
#pragma unroll
  for (int i = 0; i < 3; i++) {
    int c = tid + i * 256;           // 0..767: K chunks (64 rows x 12 chunks)
    krow[i] = c / 12;
    kco[i] = c - 12 * krow[i];
    int cc = tid + i * 256;          // 0..639: V chunks (80 rows x 8 chunks)
    vd[i] = cc >> 3;
    vco[i] = cc & 7;
  }
  bool v2 = tid < 128;               // third V chunk valid only for cc<640
  s16x8 sk[3], sv[3];
  // Q fragments (B-operand: col=l15=q, k=d)
  s16x8 qf[3];
#pragma unroll
  for (int c = 0; c < 3; c++) {
    const unsigned short* p = Q + (size_t)(qrow0 + l15) * 96 + c * 32 + kf;
    s16x4 lo = *(const s16x4*)p;
    s16x4 hi = *(const s16x4*)(p + 16);
    qf[c] = __builtin_shufflevector(lo, hi, 0, 1, 2, 3, 4, 5, 6, 7);
  }
  f32x4 o[5] = {};                   // O[q=4lq+r][d=l15+16v]
  float m_r = -3.0e38f, l_r = 0.f;   // per-lane state for q = l15

  // prologue: stage tile 0 into buf 0
#pragma unroll
  for (int i = 0; i < 3; i++)
    sk[i] = *(const s16x8*)(Kp + (size_t)krow[i] * 96 + kco[i] * 8);
#pragma unroll
  for (int i = 0; i < 2; i++)
    sv[i] = *(const s16x8*)(Vg + (size_t)vd[i] * 1024 + vco[i] * 8);
  if (v2) sv[2] = *(const s16x8*)(Vg + (size_t)vd[2] * 1024 + vco[2] * 8);
#pragma unroll
  for (int i = 0; i < 3; i++) *(s16x8*)&Kl[0][krow[i]][kco[i] * 8] = sk[i];
#pragma unroll
  for (int i = 0; i < 2; i++) *(s16x8*)&Vt[0][vd[i]][vco[i] * 8] = sv[i];
  if (v2) *(s16x8*)&Vt[0][vd[2]][vco[2] * 8] = sv[2];

  for (int tt = 0; tt < 16; tt++) {
    __syncthreads();
    int cur = tt & 1;
    if (tt < 15) {
      int kv1 = (tt + 1) * 64;
#pragma unroll
      for (int i = 0; i < 3; i++)
        sk[i] = *(const s16x8*)(Kp + (size_t)(kv1 + krow[i]) * 96 + kco[i] * 8);
#pragma unroll
      for (int i = 0; i < 2; i++)
        sv[i] = *(const s16x8*)(Vg + (size_t)vd[i] * 1024 + kv1 + vco[i] * 8);
      if (v2) sv[2] = *(const s16x8*)(Vg + (size_t)vd[2] * 1024 + kv1 + vco[2] * 8);
    }
    // S^T = mfma(K, Q): st[n][r] = S[q=l15][kv = n*16 + 4*lq + r]
    f32x4 st[4];
    __builtin_amdgcn_s_setprio(1);
#pragma unroll
    for (int n = 0; n < 4; n++) {
      f32x4 a = {};
#pragma unroll
      for (int c = 0; c < 3; c++) {
        s16x4 lo = *(const s16x4*)&Kl[cur][n * 16 + l15][c * 32 + kf];
        s16x4 hi = *(const s16x4*)&Kl[cur][n * 16 + l15][c * 32 + kf + 16];
        s16x8 kfr = __builtin_shufflevector(lo, hi, 0, 1, 2, 3, 4, 5, 6, 7);
        a = __builtin_amdgcn_mfma_f32_16x16x32_bf16(kfr, qf[c], a, 0, 0, 0);
      }
      st[n] = a;
    }
    __builtin_amdgcn_s_setprio(0);
    // online softmax for q = l15 (16 local + lq-group shfl reduce)
    float tmax = st[0][0];
#pragma unroll
    for (int n = 0; n < 4; n++)
#pragma unroll
      for (int r = 0; r < 4; r++) tmax = fmaxf(tmax, st[n][r]);
    tmax = fmaxf(tmax, __shfl_xor(tmax, 16));
    tmax = fmaxf(tmax, __shfl_xor(tmax, 32));
    float mn = fmaxf(m_r, tmax);
    float scale = __expf(m_r - mn);
    m_r = mn;
    float sum = 0.f;
#pragma unroll
    for (int n = 0; n < 4; n++)
#pragma unroll
      for (int r = 0; r < 4; r++) {
        float p = __expf(st[n][r] - mn);
        st[n][r] = p;
        sum += p;
      }
    sum += __shfl_xor(sum, 16);
    sum += __shfl_xor(sum, 32);
    l_r = l_r * scale + sum;
    // rescale O (scale for q=4lq+r lives at lane 4lq+r)
#pragma unroll
    for (int r = 0; r < 4; r++) {
      float scq = __shfl(scale, 4 * lq + r);
#pragma unroll
      for (int v = 0; v < 5; v++) o[v][r] *= scq;
    }
    // P fragments directly from st registers (A-operand: row=l15=q, k=kv)
    __builtin_amdgcn_s_setprio(1);
#pragma unroll
    for (int b = 0; b < 2; b++) {
      s16x8 pf;
#pragma unroll
      for (int j = 0; j < 8; j++) pf[j] = (short)f2b(st[2 * b + (j >> 2)][j & 3]);
#pragma unroll
      for (int v = 0; v < 5; v++) {
        s16x4 vlo = *(const s16x4*)&Vt[cur][v * 16 + l15][b * 32 + kf];
        s16x4 vhi = *(const s16x4*)&Vt[cur][v * 16 + l15][b * 32 + kf + 16];
        s16x8 vf = __builtin_shufflevector(vlo, vhi, 0, 1, 2, 3, 4, 5, 6, 7);
        o[v] = __builtin_amdgcn_mfma_f32_16x16x32_bf16(pf, vf, o[v], 0, 0, 0);
      }
    }
    __builtin_amdgcn_s_setprio(0);
    // write-late: next tile into the other buffer
    if (tt < 15) {
      int nxt = cur ^ 1;
#pragma unroll
      for (int i = 0; i < 3; i++) *(s16x8*)&Kl[nxt][krow[i]][kco[i] * 8] = sk[i];
#pragma unroll
      for (int i = 0; i < 2; i++) *(s16x8*)&Vt[nxt][vd[i]][vco[i] * 8] = sv[i];
      if (v2) *(s16x8*)&Vt[nxt][vd[2]][vco[2] * 8] = sv[2];
    }
  }
  // epilogue: normalize by l (lives at lane 4lq+r), store d<72
#pragma unroll
  for (int r = 0; r < 4; r++) {
    float inv = 1.0f / __shfl(l_r, 4 * lq + r);
    int qrow = qrow0 + 4 * lq + r;
    size_t rowbase = (size_t)(t * 1024 + qrow) * 1152 + h * 72;
#pragma unroll
    for (int v = 0; v < 5; v++) {
      int d = v * 16 + l15;
      if (d < 72) att[rowbase + d] = f2b(o[v][r] * inv);
    }
  }
}

extern "C" void kernel_launch(void* const* d_in, const int* in_sizes, int n_in,
                              void* d_out, int out_size, void* d_ws, size_t ws_size,
                              hipStream_t stream) {
  const float* x   = (const float*)d_in[0];
  const float* Wq  = (const float*)d_in[1];
  const float* bq  = (const float*)d_in[2];
  const float* Wkv = (const float*)d_in[3];
  const float* bkv = (const float*)d_in[4];
  const float* qg  = (const float*)d_in[5];
  const float* kg  = (const float*)d_in[6];
  const float* Wo  = (const float*)d_in[7];
  float* out = (float*)d_out;

  char* w = (char*)d_ws;
  unsigned short* xb   = (unsigned short*)w; w += (size_t)8192 * 1152 * 2;     // 18.9 MB
  unsigned short* WqT  = (unsigned short*)w; w += (size_t)1152 * 1152 * 2;     // contiguous with WkvT -> [3456][1152]
  unsigned short* WkvT = (unsigned short*)w; w += (size_t)2304 * 1152 * 2;
  unsigned short* WoT  = (unsigned short*)w; w += (size_t)1152 * 1152 * 2;
  unsigned short* qn   = (unsigned short*)w; w += (size_t)128 * 1024 * 96 * 2; // 25.2 MB
  unsigned short* kn   = (unsigned short*)w; w += (size_t)128 * 1024 * 96 * 2; // 25.2 MB
  unsigned short* vt   = (unsigned short*)w; w += (size_t)128 * 80 * 1024 * 2; // 21.0 MB
  unsigned short* att  = (unsigned short*)w; w += (size_t)8192 * 1152 * 2;     // 18.9 MB

  cvt_bf16_kernel<<<4608, 256, 0, stream>>>(x, xb, 9437184 / 8);
  transpose_cvt_kernel<<<dim3(36, 36), dim3(32, 8), 0, stream>>>(Wq, WqT, 1152, 1152);
  transpose_cvt_kernel<<<dim3(72, 36), dim3(32, 8), 0, stream>>>(Wkv, WkvT, 1152, 2304);
  transpose_cvt_kernel<<<dim3(36, 36), dim3(32, 8), 0, stream>>>(Wo, WoT, 1152, 1152);

  // fused q,k,v^T GEMM: BT = [WqT ; WkvT] = [3456][1152], grid 27*64=1728
  gemm_bt_kernel<3><<<1728, 256, 0, stream>>>(xb, WqT, bq, bkv, 3456, 27, nullptr, qn, kn, vt);
  rmsnorm2_kernel<<<65536, 256, 0, stream>>>(qn, kn, qg, kg);

  attn_kernel<<<2048, 256, 0, stream>>>(qn, kn, vt, att);

  // out = att @ WoT^T, grid 9*64=576
  gemm_bt_kernel<0><<<576, 256, 0, stream>>>(att, WoT, nullptr, nullptr, 1152, 9, out, nullptr, nullptr, nullptr);
}